// Round 1
// baseline (128.378 us; speedup 1.0000x reference)
//
#include <hip/hip_runtime.h>
#include <math.h>

// Problem constants (fixed by setup_inputs)
#define N_TOTAL 2097152
#define NT 256              // threads per block
#define NC 16               // elements per thread (sequential chunk)
#define EPB (NT * NC)       // 4096 elements per block
#define NB (N_TOTAL / EPB)  // 512 blocks
#define NTH (NB * NT)       // 131072 total threads

// Projective map on homogeneous (x, g, 1):
//   x' = (al*x + be) / (ga*x + de)
//   g' = (e*x + c*g + f) / (ga*x + de)
// Matrix [[al,0,be],[e,c,f],[ga,0,de]] — closed under composition.
// Compose algebra stays in DOUBLE (fp32 cancellation is marginal); the
// per-element decay P is computed in fp32 (matches the fp32 reference:
// fp32 diff of adjacent sorted fp32 t is exact, expf ~1 ulp).
struct DMat { double al, be, ga, de, c, e, f; };

__device__ __forceinline__ DMat dmat_identity() {
    DMat m; m.al = 1.0; m.be = 0.0; m.ga = 0.0; m.de = 1.0; m.c = 1.0; m.e = 0.0; m.f = 0.0;
    return m;
}

// A applied AFTER B (matrix product A*B)
__device__ __forceinline__ DMat dmat_compose(const DMat& A, const DMat& B) {
    DMat r;
    r.al = A.al * B.al + A.be * B.ga;
    r.be = A.al * B.be + A.be * B.de;
    r.ga = A.ga * B.al + A.de * B.ga;
    r.de = A.ga * B.be + A.de * B.de;
    r.c  = A.c * B.c;
    r.e  = A.e * B.al + A.c * B.e + A.f * B.ga;
    r.f  = A.e * B.be + A.c * B.f + A.f * B.de;
    return r;
}

// Scale-invariant normalization; guarded so it can never manufacture NaN/Inf.
__device__ __forceinline__ void dmat_normalize(DMat& m) {
    double mx = fmax(fabs(m.al), fabs(m.be));
    mx = fmax(mx, fabs(m.ga));
    mx = fmax(mx, fabs(m.de));
    mx = fmax(mx, fabs(m.c));
    mx = fmax(mx, fabs(m.e));
    mx = fmax(mx, fabs(m.f));
    if (!(mx > 0.0) || isinf(mx)) return;   // all-zero or corrupt: leave as-is
    double inv = 1.0 / mx;
    m.al *= inv; m.be *= inv; m.ga *= inv; m.de *= inv;
    m.c *= inv; m.e *= inv; m.f *= inv;
}

__device__ __forceinline__ void dmat_store(double* sm, int i, const DMat& m) {
    sm[0 * NT + i] = m.al; sm[1 * NT + i] = m.be; sm[2 * NT + i] = m.ga;
    sm[3 * NT + i] = m.de; sm[4 * NT + i] = m.c;  sm[5 * NT + i] = m.e;
    sm[6 * NT + i] = m.f;
}

__device__ __forceinline__ DMat dmat_load(const double* sm, int i) {
    DMat m;
    m.al = sm[0 * NT + i]; m.be = sm[1 * NT + i]; m.ga = sm[2 * NT + i];
    m.de = sm[3 * NT + i]; m.c  = sm[4 * NT + i]; m.e  = sm[5 * NT + i];
    m.f  = sm[6 * NT + i];
    return m;
}

// Ordered inclusive Hillis-Steele scan across NT threads:
// at exit sm[i] = M_i * M_{i-1} * ... * M_0, and the return value is sm[tid].
__device__ __forceinline__ DMat dmat_scan_inclusive(double* sm, DMat mine, int tid) {
    dmat_store(sm, tid, mine);
    __syncthreads();
    for (int d = 1; d < NT; d <<= 1) {
        DMat o;
        bool has = (tid >= d);
        if (has) o = dmat_load(sm, tid - d);
        __syncthreads();
        if (has) {
            mine = dmat_compose(mine, o);  // o is EARLIER -> right operand
            dmat_normalize(mine);
            dmat_store(sm, tid, mine);
        }
        __syncthreads();
    }
    return mine;
}

__device__ __forceinline__ DMat elem_mat(double P, double a, double U, double V, double yy) {
    double p = P * P;
    DMat m;
    m.al = p * (a - 2.0 * U * V);
    m.be = V * V;
    m.ga = -(p * U * U);
    m.de = a;
    m.c  = P * (a - U * V);
    m.e  = -(yy * p * U);
    m.f  = yy * V;
    return m;
}

// Register-resident 4-way select (avoid runtime-indexed array -> scratch).
__device__ __forceinline__ double band_amp(int b, double a1, double a2, double a3) {
    double lo = (b & 1) ? a1 : 1.0;
    double hi = (b & 1) ? a3 : a2;
    return (b & 2) ? hi : lo;
}

// ---------------- Kernel 1: per-thread inclusive composites ----------------
// Two independent 8-element chains per thread (2x ILP on the serial fp64
// compose chain), composed at the end; then the block-level LDS scan.
// Per-thread INCLUSIVE scan results are stored to global (SoA, coalesced)
// so the replay kernel never recomputes the chain or the scan.
__global__ __launch_bounds__(NT) void k_upsweep(
    const float* __restrict__ t, const int* __restrict__ band,
    const float* __restrict__ y, const float* __restrict__ yerr,
    const float* __restrict__ lad, const float* __restrict__ lkp,
    double* __restrict__ ptc)
{
    __shared__ double sm[7 * NT];
    const int tid = threadIdx.x;
    const double sigma2 = exp(2.0 * (double)lkp[0]);
    const float inv_ell_f = expf(-lkp[1]);
    const double amp1 = exp((double)lad[0]);
    const double amp2 = exp((double)lad[1]);
    const double amp3 = exp((double)lad[2]);

    const int gid = blockIdx.x * NT + tid;
    const int base = gid * NC;
    const bool first = (base == 0);

    float tpA = first ? 0.0f : t[base - 1];
    float tpB = t[base + NC / 2 - 1];

    DMat accA = dmat_identity();
    DMat accB = dmat_identity();

    #pragma unroll
    for (int kk = 0; kk < NC / 2; kk += 4) {
        float4 tvA = *reinterpret_cast<const float4*>(t + base + kk);
        float4 yvA = *reinterpret_cast<const float4*>(y + base + kk);
        float4 evA = *reinterpret_cast<const float4*>(yerr + base + kk);
        int4   bvA = *reinterpret_cast<const int4*>(band + base + kk);
        float4 tvB = *reinterpret_cast<const float4*>(t + base + NC / 2 + kk);
        float4 yvB = *reinterpret_cast<const float4*>(y + base + NC / 2 + kk);
        float4 evB = *reinterpret_cast<const float4*>(yerr + base + NC / 2 + kk);
        int4   bvB = *reinterpret_cast<const int4*>(band + base + NC / 2 + kk);
        float tA[4] = {tvA.x, tvA.y, tvA.z, tvA.w};
        float yA[4] = {yvA.x, yvA.y, yvA.z, yvA.w};
        float eA[4] = {evA.x, evA.y, evA.z, evA.w};
        int   bA[4] = {bvA.x, bvA.y, bvA.z, bvA.w};
        float tB[4] = {tvB.x, tvB.y, tvB.z, tvB.w};
        float yB[4] = {yvB.x, yvB.y, yvB.z, yvB.w};
        float eB[4] = {evB.x, evB.y, evB.z, evB.w};
        int   bB[4] = {bvB.x, bvB.y, bvB.z, bvB.w};
        #pragma unroll
        for (int j = 0; j < 4; ++j) {
            {   // chain A: elements [0, 8)
                double u = band_amp(bA[j], amp1, amp2, amp3);
                double U = sigma2 * u;
                double a = (double)eA[j] * (double)eA[j] + U * u;
                float dt = tA[j] - tpA; tpA = tA[j];
                double P = (first && kk == 0 && j == 0)
                         ? 0.0 : (double)expf(-dt * inv_ell_f);
                accA = dmat_compose(elem_mat(P, a, U, u, (double)yA[j]), accA);
            }
            {   // chain B: elements [8, 16) — independent of chain A
                double u = band_amp(bB[j], amp1, amp2, amp3);
                double U = sigma2 * u;
                double a = (double)eB[j] * (double)eB[j] + U * u;
                float dt = tB[j] - tpB; tpB = tB[j];
                double P = (double)expf(-dt * inv_ell_f);
                accB = dmat_compose(elem_mat(P, a, U, u, (double)yB[j]), accB);
            }
        }
    }
    DMat acc = dmat_compose(accB, accA);
    dmat_normalize(acc);
    DMat incl = dmat_scan_inclusive(sm, acc, tid);
    // SoA store: component c of thread gid at ptc[c*NTH + gid] (coalesced)
    ptc[0 * NTH + gid] = incl.al; ptc[1 * NTH + gid] = incl.be;
    ptc[2 * NTH + gid] = incl.ga; ptc[3 * NTH + gid] = incl.de;
    ptc[4 * NTH + gid] = incl.c;  ptc[5 * NTH + gid] = incl.e;
    ptc[6 * NTH + gid] = incl.f;
}

// ------ Kernel 2: spine scan -> per-block EXCLUSIVE composite matrix ------
// Block composites are read from ptc (last thread of each block).
// Also zeroes the accumulators + completion counter for this launch.
__global__ __launch_bounds__(NT) void k_spine(
    const double* __restrict__ ptc, double* __restrict__ block_excl,
    double* __restrict__ accum, unsigned int* __restrict__ done)
{
    __shared__ double sm[7 * NT];
    const int tid = threadIdx.x;
    if (tid == 0) { accum[0] = 0.0; accum[1] = 0.0; *done = 0u; }
    const int g0 = (2 * tid) * NT + (NT - 1);       // last thread of block 2*tid
    const int g1 = (2 * tid + 1) * NT + (NT - 1);   // last thread of block 2*tid+1
    DMat m0 = {ptc[0 * NTH + g0], ptc[1 * NTH + g0], ptc[2 * NTH + g0],
               ptc[3 * NTH + g0], ptc[4 * NTH + g0], ptc[5 * NTH + g0],
               ptc[6 * NTH + g0]};
    DMat m1 = {ptc[0 * NTH + g1], ptc[1 * NTH + g1], ptc[2 * NTH + g1],
               ptc[3 * NTH + g1], ptc[4 * NTH + g1], ptc[5 * NTH + g1],
               ptc[6 * NTH + g1]};
    DMat mine = dmat_compose(m1, m0);
    dmat_normalize(mine);
    dmat_scan_inclusive(sm, mine, tid);
    DMat E = (tid == 0) ? dmat_identity() : dmat_load(sm, tid - 1);
    double* o0 = block_excl + (2 * tid) * 7;
    o0[0] = E.al; o0[1] = E.be; o0[2] = E.ga; o0[3] = E.de;
    o0[4] = E.c;  o0[5] = E.e;  o0[6] = E.f;
    DMat M = dmat_compose(m0, E);
    dmat_normalize(M);
    double* o1 = block_excl + (2 * tid + 1) * 7;
    o1[0] = M.al; o1[1] = M.be; o1[2] = M.ga; o1[3] = M.de;
    o1[4] = M.c;  o1[5] = M.e;  o1[6] = M.f;
}

// ---------------- Kernel 3: replay (no recompute, no scan) ----------------
// Exclusive prefix per thread = stored inclusive of (gid-1) composed with the
// block-exclusive composite. Then a light scalar recurrence over NC elements.
// Last block to finish computes the final output (folds old k_final).
__global__ __launch_bounds__(NT) void k_replay(
    const float* __restrict__ t, const int* __restrict__ band,
    const float* __restrict__ y, const float* __restrict__ yerr,
    const float* __restrict__ lad, const float* __restrict__ lkp,
    const double* __restrict__ ptc, const double* __restrict__ block_excl,
    double* __restrict__ accum, unsigned int* __restrict__ done,
    float* __restrict__ out)
{
    const int tid = threadIdx.x;
    const int gid = blockIdx.x * NT + tid;
    const double sigma2 = exp(2.0 * (double)lkp[0]);
    const float inv_ell_f = expf(-lkp[1]);
    const double amp1 = exp((double)lad[0]);
    const double amp2 = exp((double)lad[1]);
    const double amp3 = exp((double)lad[2]);

    // full-history exclusive composite for this thread
    const double* pb = block_excl + blockIdx.x * 7;
    DMat Eb = {pb[0], pb[1], pb[2], pb[3], pb[4], pb[5], pb[6]};
    DMat F;
    if (tid == 0) {
        F = Eb;
    } else {
        const int gm1 = gid - 1;
        DMat E = {ptc[0 * NTH + gm1], ptc[1 * NTH + gm1], ptc[2 * NTH + gm1],
                  ptc[3 * NTH + gm1], ptc[4 * NTH + gm1], ptc[5 * NTH + gm1],
                  ptc[6 * NTH + gm1]};
        F = dmat_compose(E, Eb);
    }
    dmat_normalize(F);
    // apply at (x,g) = (0,0); x=0 is far from the repelling fixed point (~1)
    double x = 0.0, g = 0.0;
    if (F.de != 0.0 && !isinf(F.de)) {
        double invde = 1.0 / F.de;
        x = F.be * invde;
        g = F.f  * invde;
    }
    if (!isfinite(x)) x = 0.0;
    if (!isfinite(g)) g = 0.0;

    const int base = gid * NC;
    const bool first = (base == 0);
    float tp = first ? 0.0f : t[base - 1];

    double s_logD = 0.0, s_quad = 0.0, pd = 1.0;
    #pragma unroll
    for (int k = 0; k < NC; k += 4) {
        float4 tv = *reinterpret_cast<const float4*>(t + base + k);
        float4 yv = *reinterpret_cast<const float4*>(y + base + k);
        float4 ev = *reinterpret_cast<const float4*>(yerr + base + k);
        int4   bv = *reinterpret_cast<const int4*>(band + base + k);
        float tc[4] = {tv.x, tv.y, tv.z, tv.w};
        float yc[4] = {yv.x, yv.y, yv.z, yv.w};
        float ec[4] = {ev.x, ev.y, ev.z, ev.w};
        int   bc[4] = {bv.x, bv.y, bv.z, bv.w};
        #pragma unroll
        for (int j = 0; j < 4; ++j) {
            double u = band_amp(bc[j], amp1, amp2, amp3);
            double U = sigma2 * u;
            double a = (double)ec[j] * (double)ec[j] + U * u;
            float dt = tc[j] - tp; tp = tc[j];
            double P = (first && k == 0 && j == 0)
                     ? 0.0 : (double)expf(-dt * inv_ell_f);
            double p = P * P;
            double S = p * x;
            double D = a - U * U * S;
            if (!(D > 1e-300)) D = 1e-300;  // NaN-proof; never triggers if math is right
            double invD = 1.0 / D;
            double W = (u - S * U) * invD;
            double gn = P * g;
            double z = (double)yc[j] - U * gn;
            pd *= D;
            s_quad = fma(z * z, invD, s_quad);
            x = fma(D * W, W, S);
            g = fma(W, z, gn);
        }
        if (((k + 4) & 7) == 0) {          // fold product every 8 elements
            s_logD += log(pd);
            pd = 1.0;
        }
    }

    // in-wave reduction (no LDS tree, no barriers until the tiny cross-wave step)
    #pragma unroll
    for (int off = 32; off > 0; off >>= 1) {
        s_logD += __shfl_down(s_logD, off);
        s_quad += __shfl_down(s_quad, off);
    }
    __shared__ double red[8];
    const int wid = tid >> 6, lane = tid & 63;
    if (lane == 0) { red[wid] = s_logD; red[4 + wid] = s_quad; }
    __syncthreads();
    if (tid == 0) {
        double l = red[0] + red[1] + red[2] + red[3];
        double q = red[4] + red[5] + red[6] + red[7];
        atomicAdd(&accum[0], l);
        atomicAdd(&accum[1], q);
        __threadfence();
        unsigned int old = atomicAdd(done, 1u);
        if (old == NB - 1) {   // last block: finalize (reads via atomic RMW = coherent)
            double L = atomicAdd(&accum[0], 0.0);
            double Q = atomicAdd(&accum[1], 0.0);
            out[0] = (float)(-0.5 * (Q + L
                     + (double)N_TOTAL * 1.8378770664093454836));  // log(2*pi)
        }
    }
}

extern "C" void kernel_launch(void* const* d_in, const int* in_sizes, int n_in,
                              void* d_out, int out_size, void* d_ws, size_t ws_size,
                              hipStream_t stream)
{
    const float* t    = (const float*)d_in[0];
    const int*   band = (const int*)d_in[1];
    const float* y    = (const float*)d_in[2];
    const float* yerr = (const float*)d_in[3];
    const float* lad  = (const float*)d_in[4];
    const float* lkp  = (const float*)d_in[5];

    double* dws        = (double*)d_ws;
    double* ptc        = dws;                        // 7 * NTH doubles (7.34 MB)
    double* block_excl = dws + 7 * NTH;              // NB * 7 doubles
    double* accum      = dws + 7 * NTH + 7 * NB;     // 2 doubles
    unsigned int* done = (unsigned int*)(dws + 7 * NTH + 7 * NB + 2);

    k_upsweep<<<NB, NT, 0, stream>>>(t, band, y, yerr, lad, lkp, ptc);
    k_spine<<<1, NT, 0, stream>>>(ptc, block_excl, accum, done);
    k_replay<<<NB, NT, 0, stream>>>(t, band, y, yerr, lad, lkp,
                                    ptc, block_excl, accum, done, (float*)d_out);
}

// Round 2
// 122.608 us; speedup vs baseline: 1.0471x; 1.0471x over previous
//
#include <hip/hip_runtime.h>
#include <math.h>

// Problem constants (fixed by setup_inputs)
#define N_TOTAL 2097152
#define NT 512              // threads per block (8 waves)
#define NC 16               // elements per thread (sequential chunk)
#define EPB (NT * NC)       // 8192 elements per block
#define NB (N_TOTAL / EPB)  // 256 blocks  == #CUs -> co-residency guaranteed

// Projective map on homogeneous (x, g, 1):
//   x' = (al*x + be) / (ga*x + de)
//   g' = (e*x + c*g + f) / (ga*x + de)
// Matrix [[al,0,be],[e,c,f],[ga,0,de]] — closed under composition.
// Compose algebra stays in DOUBLE; the per-element decay P is fp32
// (fp32 diff of adjacent sorted fp32 t is exact; expf ~1 ulp — matches
// the fp32 reference).
struct DMat { double al, be, ga, de, c, e, f; };

__device__ __forceinline__ DMat dmat_identity() {
    DMat m; m.al = 1.0; m.be = 0.0; m.ga = 0.0; m.de = 1.0; m.c = 1.0; m.e = 0.0; m.f = 0.0;
    return m;
}

// A applied AFTER B (matrix product A*B)
__device__ __forceinline__ DMat dmat_compose(const DMat& A, const DMat& B) {
    DMat r;
    r.al = A.al * B.al + A.be * B.ga;
    r.be = A.al * B.be + A.be * B.de;
    r.ga = A.ga * B.al + A.de * B.ga;
    r.de = A.ga * B.be + A.de * B.de;
    r.c  = A.c * B.c;
    r.e  = A.e * B.al + A.c * B.e + A.f * B.ga;
    r.f  = A.e * B.be + A.c * B.f + A.f * B.de;
    return r;
}

// Scale-invariant normalization; guarded so it can never manufacture NaN/Inf.
__device__ __forceinline__ void dmat_normalize(DMat& m) {
    double mx = fmax(fabs(m.al), fabs(m.be));
    mx = fmax(mx, fabs(m.ga));
    mx = fmax(mx, fabs(m.de));
    mx = fmax(mx, fabs(m.c));
    mx = fmax(mx, fabs(m.e));
    mx = fmax(mx, fabs(m.f));
    if (!(mx > 0.0) || isinf(mx)) return;   // all-zero or corrupt: leave as-is
    double inv = 1.0 / mx;
    m.al *= inv; m.be *= inv; m.ga *= inv; m.de *= inv;
    m.c *= inv; m.e *= inv; m.f *= inv;
}

__device__ __forceinline__ void dmat_store(double* sm, int i, const DMat& m) {
    sm[0 * NT + i] = m.al; sm[1 * NT + i] = m.be; sm[2 * NT + i] = m.ga;
    sm[3 * NT + i] = m.de; sm[4 * NT + i] = m.c;  sm[5 * NT + i] = m.e;
    sm[6 * NT + i] = m.f;
}

__device__ __forceinline__ DMat dmat_load(const double* sm, int i) {
    DMat m;
    m.al = sm[0 * NT + i]; m.be = sm[1 * NT + i]; m.ga = sm[2 * NT + i];
    m.de = sm[3 * NT + i]; m.c  = sm[4 * NT + i]; m.e  = sm[5 * NT + i];
    m.f  = sm[6 * NT + i];
    return m;
}

// Ordered inclusive Hillis-Steele scan across NT threads:
// at exit sm[i] = M_i * ... * M_0, return value = sm[tid].
__device__ __forceinline__ DMat dmat_scan_inclusive(double* sm, DMat mine, int tid) {
    dmat_store(sm, tid, mine);
    __syncthreads();
    for (int d = 1; d < NT; d <<= 1) {
        DMat o;
        bool has = (tid >= d);
        if (has) o = dmat_load(sm, tid - d);
        __syncthreads();
        if (has) {
            mine = dmat_compose(mine, o);  // o is EARLIER -> right operand
            dmat_normalize(mine);
            dmat_store(sm, tid, mine);
        }
        __syncthreads();
    }
    return mine;
}

// Inclusive scan over the first NB (=256) entries of sm; all NT threads
// execute the barriers (no barrier inside divergent flow).
__device__ __forceinline__ void dmat_scan_spine(double* sm, int tid) {
    for (int d = 1; d < NB; d <<= 1) {
        DMat mine, o;
        bool has = (tid >= d) && (tid < NB);
        if (has) { mine = dmat_load(sm, tid); o = dmat_load(sm, tid - d); }
        __syncthreads();
        if (has) {
            mine = dmat_compose(mine, o);
            dmat_normalize(mine);
            dmat_store(sm, tid, mine);
        }
        __syncthreads();
    }
}

__device__ __forceinline__ DMat elem_mat(double P, double a, double U, double V, double yy) {
    double p = P * P;
    DMat m;
    m.al = p * (a - 2.0 * U * V);
    m.be = V * V;
    m.ga = -(p * U * U);
    m.de = a;
    m.c  = P * (a - U * V);
    m.e  = -(yy * p * U);
    m.f  = yy * V;
    return m;
}

// Register-resident 4-way select (avoid runtime-indexed array -> scratch).
__device__ __forceinline__ double band_amp(int b, double a1, double a2, double a3) {
    double lo = (b & 1) ? a1 : 1.0;
    double hi = (b & 1) ? a3 : a2;
    return (b & 2) ? hi : lo;
}

// ------------------------- single fused kernel ---------------------------
// phase 1: per-thread chain (element data cached in registers) + block scan
// grid barrier (hand-rolled; 256 blocks = 1/CU -> always co-resident)
// phase 2: redundant spine scan of 256 block composites in EVERY block
// phase 3: replay from registers, block reduce, done-counter finalize
__global__ __launch_bounds__(NT) void k_fused(
    const float* __restrict__ t, const int* __restrict__ band,
    const float* __restrict__ y, const float* __restrict__ yerr,
    const float* __restrict__ lad, const float* __restrict__ lkp,
    double* __restrict__ L, double* __restrict__ accum,
    unsigned int* __restrict__ bar0, unsigned int* __restrict__ done,
    float* __restrict__ out)
{
    __shared__ double sm[7 * NT];
    __shared__ double red[16];
    const int tid = threadIdx.x;
    const int bid = blockIdx.x;

    const double sigma2 = exp(2.0 * (double)lkp[0]);
    const float inv_ell_f = expf(-lkp[1]);
    const double amp1 = exp((double)lad[0]);
    const double amp2 = exp((double)lad[1]);
    const double amp3 = exp((double)lad[2]);

    const int gid = bid * NT + tid;
    const int base = gid * NC;
    const bool first = (base == 0);

    // per-element data, register-resident for the replay phase
    float Pv[NC], av[NC], Uv[NC], Vv[NC], yvv[NC];

    float tpA = first ? 0.0f : t[base - 1];
    float tpB = t[base + NC / 2 - 1];

    DMat accA = dmat_identity();
    DMat accB = dmat_identity();

    #pragma unroll
    for (int kk = 0; kk < NC / 2; kk += 4) {
        float4 tvA = *reinterpret_cast<const float4*>(t + base + kk);
        float4 yvA = *reinterpret_cast<const float4*>(y + base + kk);
        float4 evA = *reinterpret_cast<const float4*>(yerr + base + kk);
        int4   bvA = *reinterpret_cast<const int4*>(band + base + kk);
        float4 tvB = *reinterpret_cast<const float4*>(t + base + NC / 2 + kk);
        float4 yvB = *reinterpret_cast<const float4*>(y + base + NC / 2 + kk);
        float4 evB = *reinterpret_cast<const float4*>(yerr + base + NC / 2 + kk);
        int4   bvB = *reinterpret_cast<const int4*>(band + base + NC / 2 + kk);
        float tA[4] = {tvA.x, tvA.y, tvA.z, tvA.w};
        float yA[4] = {yvA.x, yvA.y, yvA.z, yvA.w};
        float eA[4] = {evA.x, evA.y, evA.z, evA.w};
        int   bA[4] = {bvA.x, bvA.y, bvA.z, bvA.w};
        float tB[4] = {tvB.x, tvB.y, tvB.z, tvB.w};
        float yB[4] = {yvB.x, yvB.y, yvB.z, yvB.w};
        float eB[4] = {evB.x, evB.y, evB.z, evB.w};
        int   bB[4] = {bvB.x, bvB.y, bvB.z, bvB.w};
        #pragma unroll
        for (int j = 0; j < 4; ++j) {
            {   // chain A: elements [0, 8)
                double u = band_amp(bA[j], amp1, amp2, amp3);
                double U = sigma2 * u;
                double a = (double)eA[j] * (double)eA[j] + U * u;
                float dt = tA[j] - tpA; tpA = tA[j];
                float pf = (first && kk == 0 && j == 0)
                         ? 0.0f : expf(-dt * inv_ell_f);
                Pv[kk + j] = pf; av[kk + j] = (float)a;
                Uv[kk + j] = (float)U; Vv[kk + j] = (float)u;
                yvv[kk + j] = yA[j];
                accA = dmat_compose(elem_mat((double)pf, a, U, u, (double)yA[j]), accA);
            }
            {   // chain B: elements [8, 16) — independent of chain A
                double u = band_amp(bB[j], amp1, amp2, amp3);
                double U = sigma2 * u;
                double a = (double)eB[j] * (double)eB[j] + U * u;
                float dt = tB[j] - tpB; tpB = tB[j];
                float pf = expf(-dt * inv_ell_f);
                int ix = 8 + kk + j;
                Pv[ix] = pf; av[ix] = (float)a;
                Uv[ix] = (float)U; Vv[ix] = (float)u;
                yvv[ix] = yB[j];
                accB = dmat_compose(elem_mat((double)pf, a, U, u, (double)yB[j]), accB);
            }
        }
    }
    DMat acc = dmat_compose(accB, accA);
    dmat_normalize(acc);
    DMat incl = dmat_scan_inclusive(sm, acc, tid);

    // thread-level exclusive prefix (within block), extracted BEFORE sm reuse
    DMat Et = (tid == 0) ? dmat_identity() : dmat_load(sm, tid - 1);

    // publish block composite
    if (tid == NT - 1) {
        double* o = L + bid * 7;
        o[0] = incl.al; o[1] = incl.be; o[2] = incl.ga; o[3] = incl.de;
        o[4] = incl.c;  o[5] = incl.e;  o[6] = incl.f;
    }

    // ---- grid barrier (single): all L[] published before anyone reads ----
    __syncthreads();                    // drains the L store (vmcnt) too
    if (tid == 0) {
        __threadfence();                // device-scope release of L[bid]
        atomicAdd(bar0, 1u);
        while (__hip_atomic_load(bar0, __ATOMIC_ACQUIRE,
                                 __HIP_MEMORY_SCOPE_AGENT) < NB) {
            __builtin_amdgcn_s_sleep(2);
        }
    }
    __syncthreads();

    // ---- redundant spine scan (every block; parallel; no 2nd barrier) ----
    if (tid < NB) {
        const double* p = L + tid * 7;
        DMat m = {p[0], p[1], p[2], p[3], p[4], p[5], p[6]};
        dmat_store(sm, tid, m);
    }
    __syncthreads();
    dmat_scan_spine(sm, tid);
    DMat Eb = dmat_identity();
    if (bid > 0) Eb = dmat_load(sm, bid - 1);   // uniform -> LDS broadcast

    // full-history exclusive composite for this thread
    DMat F = dmat_compose(Et, Eb);
    dmat_normalize(F);
    // apply at (x,g) = (0,0); x=0 is far from the repelling fixed point (~1)
    double x = 0.0, g = 0.0;
    if (F.de != 0.0 && !isinf(F.de)) {
        double invde = 1.0 / F.de;
        x = F.be * invde;
        g = F.f  * invde;
    }
    if (!isfinite(x)) x = 0.0;
    if (!isfinite(g)) g = 0.0;

    // ---- replay from registers: no global re-reads, no recompute ----
    double s_logD = 0.0, s_quad = 0.0, pd = 1.0;
    #pragma unroll
    for (int k = 0; k < NC; ++k) {
        double P = (double)Pv[k], a = (double)av[k], U = (double)Uv[k];
        double V = (double)Vv[k], yy = (double)yvv[k];
        double p = P * P;
        double S = p * x;
        double D = a - U * U * S;
        if (!(D > 1e-300)) D = 1e-300;  // NaN-proof; never triggers if math is right
        double invD = 1.0 / D;
        double W = (V - S * U) * invD;
        double gn = P * g;
        double z = yy - U * gn;
        pd *= D;
        s_quad = fma(z * z, invD, s_quad);
        x = fma(D * W, W, S);
        g = fma(W, z, gn);
        if ((k & 7) == 7) {            // fold product every 8 elements
            s_logD += log(pd);
            pd = 1.0;
        }
    }

    // in-wave reduction, then tiny cross-wave step
    #pragma unroll
    for (int off = 32; off > 0; off >>= 1) {
        s_logD += __shfl_down(s_logD, off);
        s_quad += __shfl_down(s_quad, off);
    }
    const int wid = tid >> 6, lane = tid & 63;
    if (lane == 0) { red[wid] = s_logD; red[8 + wid] = s_quad; }
    __syncthreads();
    if (tid == 0) {
        double l = 0.0, q = 0.0;
        #pragma unroll
        for (int w = 0; w < 8; ++w) { l += red[w]; q += red[8 + w]; }
        atomicAdd(&accum[0], l);
        atomicAdd(&accum[1], q);
        __threadfence();
        unsigned int old = atomicAdd(done, 1u);
        if (old == NB - 1) {   // last block: finalize (atomic RMW reads = coherent)
            double LL = atomicAdd(&accum[0], 0.0);
            double QQ = atomicAdd(&accum[1], 0.0);
            out[0] = (float)(-0.5 * (QQ + LL
                     + (double)N_TOTAL * 1.8378770664093454836));  // log(2*pi)
        }
    }
}

extern "C" void kernel_launch(void* const* d_in, const int* in_sizes, int n_in,
                              void* d_out, int out_size, void* d_ws, size_t ws_size,
                              hipStream_t stream)
{
    const float* t    = (const float*)d_in[0];
    const int*   band = (const int*)d_in[1];
    const float* y    = (const float*)d_in[2];
    const float* yerr = (const float*)d_in[3];
    const float* lad  = (const float*)d_in[4];
    const float* lkp  = (const float*)d_in[5];

    double* dws        = (double*)d_ws;
    double* accum      = dws;                         // 2 doubles (16 B)
    unsigned int* ctrs = (unsigned int*)(dws + 2);    // bar0, done (+pad) 16 B
    double* L          = dws + 4;                     // NB * 7 doubles (14 KB)

    // zero the control words (workspace is poisoned between iterations)
    hipMemsetAsync(dws, 0, 32, stream);
    k_fused<<<NB, NT, 0, stream>>>(t, band, y, yerr, lad, lkp,
                                   L, accum, ctrs, ctrs + 1, (float*)d_out);
}